// Round 4
// baseline (616.692 us; speedup 1.0000x reference)
//
#include <hip/hip_runtime.h>
#include <hip/hip_bf16.h>

#define HF 64
#define EPS 1e-5f

#define BSH 9                    // bucket shift: 512 nodes / bucket
#define BKN (1 << BSH)           // 512 nodes per bucket
#define NBUCK_MAX 256            // >= ceil(N / BKN)
#define PB_T 256                 // passB threads
#define PB_EPT 32                // edges per thread
#define PB_TILE (PB_T * PB_EPT)  // 8192 edges per block

#define LGRID 2048               // k_layer grid: grid-stride over nodes

typedef __hip_bfloat16 bf16;

__device__ __forceinline__ unsigned char f32_to_fp8(float v) {
    int p = __builtin_amdgcn_cvt_pk_fp8_f32(v, v, 0, false);
    return (unsigned char)(p & 0xff);
}

__device__ __forceinline__ float rdlane(float v, int k) {
    return __int_as_float(__builtin_amdgcn_readlane(__float_as_int(v), k));
}

__device__ __forceinline__ unsigned bf16_rne_hi(float x) {
    unsigned u = __float_as_uint(x);
    return (u + 0x7fffu + ((u >> 16) & 1u)) & 0xffff0000u;  // rounded, kept in high half
}

// ---- bucket histogram: LDS per-block, one global atomic per (block,bucket) ----
__global__ __launch_bounds__(PB_T) void k_bhist(const int* __restrict__ dst,
                                                int* __restrict__ bcnt, int E, int B) {
    __shared__ int bh[NBUCK_MAX];
    int t = threadIdx.x;
    for (int b = t; b < B; b += PB_T) bh[b] = 0;
    __syncthreads();
    int tile0 = blockIdx.x * PB_TILE;
#pragma unroll
    for (int k = 0; k < PB_EPT; ++k) {
        int e = tile0 + k * PB_T + t;
        if (e < E) atomicAdd(&bh[dst[e] >> BSH], 1);
    }
    __syncthreads();
    for (int b = t; b < B; b += PB_T) {
        int c = bh[b];
        if (c) atomicAdd(&bcnt[b], c);
    }
}

// ---- bucket scan: bbase2 = excl scan(bcnt); bcur = bbase2; base[N] = E ----
__global__ void k_bscan(const int* __restrict__ bcnt, int* __restrict__ bbase2,
                        int* __restrict__ bcur, int* __restrict__ base, int B, int N, int E) {
    if (threadIdx.x == 0 && blockIdx.x == 0) {
        int acc = 0;
        for (int i = 0; i < B; ++i) { bbase2[i] = acc; bcur[i] = acc; acc += bcnt[i]; }
        bbase2[B] = acc;   // == E
        base[N] = E;
    }
}

// ---- pass B: block-tiled binning; reserve per-(block,bucket) RUNS, write block-private ----
__global__ __launch_bounds__(PB_T) void k_passB(
    const int* __restrict__ src, const int* __restrict__ dst,
    int* __restrict__ bcur, int* __restrict__ stage, int E, int B) {
    __shared__ int scnt[NBUCK_MAX];
    __shared__ int sgoff[NBUCK_MAX];
    int t = threadIdx.x;
    int tile0 = blockIdx.x * PB_TILE;

    for (int b = t; b < B; b += PB_T) scnt[b] = 0;
    __syncthreads();

    int rec[PB_EPT];
    int bkt[PB_EPT];
#pragma unroll
    for (int k = 0; k < PB_EPT; ++k) {
        int e = tile0 + k * PB_T + t;
        bkt[k] = -1;
        if (e < E) {
            int d = dst[e];
            int s = src[e];
            int b = d >> BSH;
            bkt[k] = b;
            rec[k] = s | ((d & (BKN - 1)) << 17);
            atomicAdd(&scnt[b], 1);
        }
    }
    __syncthreads();

    for (int b = t; b < B; b += PB_T) {
        int c = scnt[b];
        sgoff[b] = c ? atomicAdd(&bcur[b], c) : 0;
        scnt[b] = 0;
    }
    __syncthreads();

#pragma unroll
    for (int k = 0; k < PB_EPT; ++k) {
        if (bkt[k] >= 0) {
            int loc = atomicAdd(&scnt[bkt[k]], 1);
            stage[sgoff[bkt[k]] + loc] = rec[k];
        }
    }
}

// ---- pass C: per bucket: LDS node-hist -> scan -> base/dinv -> scatter csr ----
__global__ __launch_bounds__(512) void k_passC(const int* __restrict__ stage,
                                               const int* __restrict__ bb2,
                                               int* __restrict__ base,
                                               float* __restrict__ dinv,
                                               int* __restrict__ csr, int N) {
    __shared__ int lcnt[BKN];
    __shared__ int lscan[BKN];
    __shared__ int lcur[BKN];
    int beta = blockIdx.x;
    int n0 = beta * BKN;
    int n1 = n0 + BKN; if (n1 > N) n1 = N;
    int nn = n1 - n0;
    int t = threadIdx.x;       // blockDim == 512 == BKN
    lcnt[t] = 0;
    __syncthreads();
    int rbeg = bb2[beta], rend = bb2[beta + 1];
    for (int i = rbeg + t; i < rend; i += 512)
        atomicAdd(&lcnt[stage[i] >> 17], 1);
    __syncthreads();
    int v = lcnt[t];
    lscan[t] = v;
    __syncthreads();
    for (int off = 1; off < 512; off <<= 1) {
        int val = lscan[t];
        int add = (t >= off) ? lscan[t - off] : 0;
        __syncthreads();
        lscan[t] = val + add;
        __syncthreads();
    }
    int b = rbeg + lscan[t] - v;   // exclusive scan + bucket start
    if (t < nn) {
        base[n0 + t] = b;
        dinv[n0 + t] = rsqrtf((float)v + 1.0f);
    }
    lcur[t] = b;
    __syncthreads();
    for (int i = rbeg + t; i < rend; i += 512) {
        int r = stage[i];
        int pos = atomicAdd(&lcur[r >> 17], 1);
        csr[pos] = r & 0x1ffff;
    }
}

// ---- prescale: xs[n,c] = x[n,c] * dinv[n] ----
__global__ void k_prescale(const float* __restrict__ x, const float* __restrict__ dinv,
                           float* __restrict__ xs, int N5) {
    int i = blockIdx.x * blockDim.x + threadIdx.x;
    if (i < N5) xs[i] = x[i] * dinv[i / 5];
}

// ---- layer 1 fused: multi-neighbor gather (8 neighbors / wave VMEM instr) ----
// lane = g*8 + c, g in 0..7 (neighbor slot), c in 0..7 (feature, c<5 useful).
// xs is padded, so c=5..7 over-reads are safe + discarded.
__global__ __launch_bounds__(256, 6) void k_layer1(
    const float* __restrict__ xs, unsigned char* __restrict__ hout,
    const int* __restrict__ csr, const int* __restrict__ basep,
    const float* __restrict__ dinv,
    const float* __restrict__ W1, const float* __restrict__ b,
    const float* __restrict__ g, const float* __restrict__ be,
    const float* __restrict__ rm, const float* __restrict__ rv, int N) {
    __shared__ float sW[5 * HF];
    __shared__ float sB[HF];
    __shared__ float sScale[HF];
    if (threadIdx.x < HF) {
        int f = threadIdx.x;
        float scale = g[f] * rsqrtf(rv[f] + EPS);
        sScale[f] = scale;
        sB[f] = (b[f] - rm[f]) * scale + be[f];
    }
    __syncthreads();
    for (int i = threadIdx.x; i < 5 * HF; i += blockDim.x)
        sW[i] = W1[i] * sScale[i & (HF - 1)];
    __syncthreads();

    int lane = threadIdx.x & 63;
    int wave = threadIdx.x >> 6;
    int c  = lane & 7;     // feature (c<5 useful)
    int g8 = lane >> 3;    // neighbor slot 0..7
    int stride = gridDim.x * 4;

    for (int node = blockIdx.x * 4 + wave; node < N; node += stride) {
        int j   = __builtin_amdgcn_readfirstlane(basep[node]);
        int end = __builtin_amdgcn_readfirstlane(basep[node + 1]);

        // self term: slot 0 only (counted once after the cross-slot reduction)
        float a0 = 0.f, a1 = 0.f, a2 = 0.f, a3 = 0.f;
        if (g8 == 0 && c < 5) a0 = xs[node * 5 + c];

        // 32 neighbors / iteration: 4 vector csr loads + 4 gathers in flight
        for (; j + 32 <= end; j += 32) {
            int s0 = csr[j + g8];
            int s1 = csr[j + 8 + g8];
            int s2 = csr[j + 16 + g8];
            int s3 = csr[j + 24 + g8];
            float v0 = xs[s0 * 5 + c];   // c>=5 lanes read pad garbage; discarded below
            float v1 = xs[s1 * 5 + c];
            float v2 = xs[s2 * 5 + c];
            float v3 = xs[s3 * 5 + c];
            a0 += v0; a1 += v1; a2 += v2; a3 += v3;
        }
        for (; j + 8 <= end; j += 8) {
            int s = csr[j + g8];
            a0 += xs[s * 5 + c];
        }
        if (j < end) {                    // tail <8: slot g8 takes neighbor j+g8
            if (j + g8 < end) {
                int s = csr[j + g8];
                a0 += xs[s * 5 + c];
            }
        }

        // fold the 8 neighbor slots: xor over g bits (3,4,5)
        float acc = (a0 + a1) + (a2 + a3);
        acc += __shfl_xor(acc, 8, 64);
        acc += __shfl_xor(acc, 16, 64);
        acc += __shfl_xor(acc, 32, 64);

        float di = dinv[node];
        acc *= di;

        float out = sB[lane];
#pragma unroll
        for (int k = 0; k < 5; ++k) out += __shfl(acc, k, 64) * sW[k * HF + lane];
        out = fmaxf(out, 0.f);
        hout[(size_t)node * HF + lane] = f32_to_fp8(out * di);  // pre-scale for next layer
    }
}

// ---- layers 2/3 fused: byte-gather + bf16-PACKED register weights + readlane MLP ----
// Weight column (64 floats) packed as 32 dwords of 2xbf16 -> stays register-resident
// at VGPR<=~72 (fp32 weights at 64 VGPR forced the compiler to re-load W per node).
// ZERO LDS. __launch_bounds__(256,6): pin 6 waves/EU for gather-latency hiding.
// SCALE_OUT=1: write fp8 hs = h*dinv. SCALE_OUT=0: write fp32 h (feeds pool).
template <int SCALE_OUT>
__global__ __launch_bounds__(256, 6) void k_layer(
    const unsigned char* __restrict__ hs8, void* __restrict__ hout_v,
    const int* __restrict__ csr, const int* __restrict__ basep,
    const float* __restrict__ dinv,
    const float* __restrict__ W, const float* __restrict__ b,
    const float* __restrict__ g, const float* __restrict__ be,
    const float* __restrict__ rm, const float* __restrict__ rv, int N) {
    int lane = threadIdx.x & 63;
    int wave = threadIdx.x >> 6;
    int stride = gridDim.x * 4;
    const unsigned char* col = hs8 + lane;   // lane's feature column

    // fold BN into per-lane scale/bias; pack weight column as bf16 pairs
    float scale = g[lane] * rsqrtf(rv[lane] + EPS);
    float bias  = (b[lane] - rm[lane]) * scale + be[lane];
    unsigned wp[HF / 2];
#pragma unroll
    for (int k2 = 0; k2 < HF / 2; ++k2) {
        unsigned lo = bf16_rne_hi(W[(2 * k2 + 0) * HF + lane] * scale);
        unsigned hi = bf16_rne_hi(W[(2 * k2 + 1) * HF + lane] * scale);
        wp[k2] = (lo >> 16) | hi;
    }

    for (int node = blockIdx.x * 4 + wave; node < N; node += stride) {
        int j   = __builtin_amdgcn_readfirstlane(basep[node]);
        int end = __builtin_amdgcn_readfirstlane(basep[node + 1]);

        // self term (already *dinv[src])
        float a0 = __builtin_amdgcn_cvt_f32_fp8((unsigned)col[(size_t)node * HF], 0);
        float a1 = 0.f, a2 = 0.f, a3 = 0.f;

        // 16-wide: 16 scalar csr loads (wave-uniform j -> s_load) then 16
        // independent coalesced byte-gathers all in flight before first use
        for (; j + 16 <= end; j += 16) {
            int s0 = csr[j+0],  s1 = csr[j+1],  s2 = csr[j+2],  s3 = csr[j+3];
            int s4 = csr[j+4],  s5 = csr[j+5],  s6 = csr[j+6],  s7 = csr[j+7];
            int s8 = csr[j+8],  s9 = csr[j+9],  sA = csr[j+10], sB_ = csr[j+11];
            int sC = csr[j+12], sD = csr[j+13], sE = csr[j+14], sF = csr[j+15];
            unsigned u0 = col[(size_t)s0 * HF];
            unsigned u1 = col[(size_t)s1 * HF];
            unsigned u2 = col[(size_t)s2 * HF];
            unsigned u3 = col[(size_t)s3 * HF];
            unsigned u4 = col[(size_t)s4 * HF];
            unsigned u5 = col[(size_t)s5 * HF];
            unsigned u6 = col[(size_t)s6 * HF];
            unsigned u7 = col[(size_t)s7 * HF];
            unsigned u8 = col[(size_t)s8 * HF];
            unsigned u9 = col[(size_t)s9 * HF];
            unsigned uA = col[(size_t)sA * HF];
            unsigned uB = col[(size_t)sB_ * HF];
            unsigned uC = col[(size_t)sC * HF];
            unsigned uD = col[(size_t)sD * HF];
            unsigned uE = col[(size_t)sE * HF];
            unsigned uF = col[(size_t)sF * HF];
            a0 += __builtin_amdgcn_cvt_f32_fp8(u0, 0);
            a1 += __builtin_amdgcn_cvt_f32_fp8(u1, 0);
            a2 += __builtin_amdgcn_cvt_f32_fp8(u2, 0);
            a3 += __builtin_amdgcn_cvt_f32_fp8(u3, 0);
            a0 += __builtin_amdgcn_cvt_f32_fp8(u4, 0);
            a1 += __builtin_amdgcn_cvt_f32_fp8(u5, 0);
            a2 += __builtin_amdgcn_cvt_f32_fp8(u6, 0);
            a3 += __builtin_amdgcn_cvt_f32_fp8(u7, 0);
            a0 += __builtin_amdgcn_cvt_f32_fp8(u8, 0);
            a1 += __builtin_amdgcn_cvt_f32_fp8(u9, 0);
            a2 += __builtin_amdgcn_cvt_f32_fp8(uA, 0);
            a3 += __builtin_amdgcn_cvt_f32_fp8(uB, 0);
            a0 += __builtin_amdgcn_cvt_f32_fp8(uC, 0);
            a1 += __builtin_amdgcn_cvt_f32_fp8(uD, 0);
            a2 += __builtin_amdgcn_cvt_f32_fp8(uE, 0);
            a3 += __builtin_amdgcn_cvt_f32_fp8(uF, 0);
        }
        for (; j + 4 <= end; j += 4) {
            int s0 = csr[j+0], s1 = csr[j+1], s2 = csr[j+2], s3 = csr[j+3];
            unsigned u0 = col[(size_t)s0 * HF];
            unsigned u1 = col[(size_t)s1 * HF];
            unsigned u2 = col[(size_t)s2 * HF];
            unsigned u3 = col[(size_t)s3 * HF];
            a0 += __builtin_amdgcn_cvt_f32_fp8(u0, 0);
            a1 += __builtin_amdgcn_cvt_f32_fp8(u1, 0);
            a2 += __builtin_amdgcn_cvt_f32_fp8(u2, 0);
            a3 += __builtin_amdgcn_cvt_f32_fp8(u3, 0);
        }
        for (; j < end; ++j) {
            int s = csr[j];
            a0 += __builtin_amdgcn_cvt_f32_fp8((unsigned)col[(size_t)s * HF], 0);
        }
        float di = dinv[node];
        float acc = ((a0 + a1) + (a2 + a3)) * di;

        // readlane MLP against packed bf16 register weights (no memory traffic).
        float o0 = bias, o1 = 0.f, o2 = 0.f, o3 = 0.f;
#pragma unroll
        for (int k = 0; k < HF; k += 4) {
            unsigned pA = wp[k / 2 + 0];
            unsigned pB = wp[k / 2 + 1];
            o0 += rdlane(acc, k + 0) * __uint_as_float(pA << 16);
            o1 += rdlane(acc, k + 1) * __uint_as_float(pA & 0xffff0000u);
            o2 += rdlane(acc, k + 2) * __uint_as_float(pB << 16);
            o3 += rdlane(acc, k + 3) * __uint_as_float(pB & 0xffff0000u);
        }
        float out = fmaxf((o0 + o1) + (o2 + o3), 0.f);
        if (SCALE_OUT) {
            ((unsigned char*)hout_v)[(size_t)node * HF + lane] = f32_to_fp8(out * di);
        } else {
            ((float*)hout_v)[(size_t)node * HF + lane] = out;
        }
    }
}

// ---- per-graph mean-pool + FC(64->32) relu + FC(32->2) sigmoid ----
__global__ void k_pool_fc(const float* __restrict__ h, const int* __restrict__ batch,
                          const float* __restrict__ Wf1, const float* __restrict__ bf1,
                          const float* __restrict__ Wf2, const float* __restrict__ bf2,
                          float* __restrict__ out, int N) {
    int g = blockIdx.x;
    int t = threadIdx.x;
    int f = t & 63, q = t >> 6;

    int lo = 0, hi = N;
    while (lo < hi) { int mid = (lo + hi) >> 1; if (batch[mid] < g) lo = mid + 1; else hi = mid; }
    int start = lo;
    hi = N;
    while (lo < hi) { int mid = (lo + hi) >> 1; if (batch[mid] < g + 1) lo = mid + 1; else hi = mid; }
    int end = lo;

    float sum = 0.f;
    for (int n = start + q; n < end; n += 4) sum += h[n * HF + f];

    __shared__ float red[4][HF];
    __shared__ float sp[HF];
    __shared__ float sh[32];
    red[q][f] = sum;
    __syncthreads();
    if (q == 0) {
        float s = red[0][f] + red[1][f] + red[2][f] + red[3][f];
        float cntf = (float)(end - start);
        sp[f] = s / fmaxf(cntf, 1.0f);
    }
    __syncthreads();
    if (t < 32) {
        float a = bf1[t];
#pragma unroll
        for (int k = 0; k < HF; ++k) a += sp[k] * Wf1[k * 32 + t];
        sh[t] = fmaxf(a, 0.f);
    }
    __syncthreads();
    if (t < 2) {
        float a = bf2[t];
#pragma unroll
        for (int k = 0; k < 32; ++k) a += sh[k] * Wf2[k * 2 + t];
        out[g * 2 + t] = 1.f / (1.f + expf(-a));
    }
}

extern "C" void kernel_launch(void* const* d_in, const int* in_sizes, int n_in,
                              void* d_out, int out_size, void* d_ws, size_t ws_size,
                              hipStream_t stream) {
    const float* x     = (const float*)d_in[0];
    const int*   ei    = (const int*)d_in[1];
    const int*   batch = (const int*)d_in[2];
    const float* W1 = (const float*)d_in[3];
    const float* b1 = (const float*)d_in[4];
    const float* g1 = (const float*)d_in[5];
    const float* be1 = (const float*)d_in[6];
    const float* rm1 = (const float*)d_in[7];
    const float* rv1 = (const float*)d_in[8];
    const float* W2 = (const float*)d_in[9];
    const float* b2 = (const float*)d_in[10];
    const float* g2 = (const float*)d_in[11];
    const float* be2 = (const float*)d_in[12];
    const float* rm2 = (const float*)d_in[13];
    const float* rv2 = (const float*)d_in[14];
    const float* W3 = (const float*)d_in[15];
    const float* b3 = (const float*)d_in[16];
    const float* g3 = (const float*)d_in[17];
    const float* be3 = (const float*)d_in[18];
    const float* rm3 = (const float*)d_in[19];
    const float* rv3 = (const float*)d_in[20];
    const float* Wf1 = (const float*)d_in[21];
    const float* bf1 = (const float*)d_in[22];
    const float* Wf2 = (const float*)d_in[23];
    const float* bf2 = (const float*)d_in[24];
    float* out = (float*)d_out;

    const int N = in_sizes[2];            // 100000
    const int E = in_sizes[1] / 2;        // 3200000
    const int G = out_size / 2;           // 256
    const int B = (N + BKN - 1) / BKN;    // buckets (196)

    char* ws = (char*)d_ws;
    size_t off = 0;
    auto alloc = [&](size_t bytes) {
        char* p = ws + off;
        off += (bytes + 255) & ~(size_t)255;
        return p;
    };
    float*         H3       = (float*)alloc((size_t)N * HF * sizeof(float));
    unsigned char* HS1      = (unsigned char*)alloc((size_t)N * HF);
    unsigned char* HS2      = (unsigned char*)alloc((size_t)N * HF);
    float*         xs       = (float*)alloc((size_t)N * 5 * sizeof(float) + 64);  // +pad: c=5..7 over-read
    float*         dinv     = (float*)alloc((size_t)N * sizeof(float));
    int*           base     = (int*)  alloc(((size_t)N + 1) * sizeof(int));
    int*           bcnt     = (int*)  alloc((size_t)NBUCK_MAX * sizeof(int));
    int*           bbase2   = (int*)  alloc(((size_t)NBUCK_MAX + 1) * sizeof(int));
    int*           bcur     = (int*)  alloc((size_t)NBUCK_MAX * sizeof(int));
    int*           csr      = (int*)  alloc((size_t)E * sizeof(int));
    int*           stage    = (int*)H3;   // alias: consumed (passC) before H3 written (layer 3)

    const int* src = ei;
    const int* dst = ei + E;

    const int BT = 256;
    int gP  = (N * 5 + BT - 1) / BT;
    int gPB = (E + PB_TILE - 1) / PB_TILE;

    // ---- CSR build: bucket hist -> 196-scan -> run-reserving partition -> local scatter ----
    hipMemsetAsync(bcnt, 0, (size_t)B * sizeof(int), stream);
    k_bhist<<<gPB, PB_T, 0, stream>>>(dst, bcnt, E, B);
    k_bscan<<<1, 64, 0, stream>>>(bcnt, bbase2, bcur, base, B, N, E);
    k_passB<<<gPB, PB_T, 0, stream>>>(src, dst, bcur, stage, E, B);
    k_passC<<<B, 512, 0, stream>>>(stage, bbase2, base, dinv, csr, N);
    k_prescale<<<gP, BT, 0, stream>>>(x, dinv, xs, N * 5);

    // ---- fused layers (weights in registers; grid-stride over nodes) ----
    k_layer1<<<LGRID, BT, 0, stream>>>(xs, HS1, csr, base, dinv,
                                       W1, b1, g1, be1, rm1, rv1, N);
    k_layer<1><<<LGRID, BT, 0, stream>>>(HS1, HS2, csr, base, dinv,
                                         W2, b2, g2, be2, rm2, rv2, N);
    k_layer<0><<<LGRID, BT, 0, stream>>>(HS2, H3, csr, base, dinv,
                                         W3, b3, g3, be3, rm3, rv3, N);

    // ---- pool + MLP head ----
    k_pool_fc<<<G, BT, 0, stream>>>(H3, batch, Wf1, bf1, Wf2, bf2, out, N);
}

// Round 5
// 459.588 us; speedup vs baseline: 1.3418x; 1.3418x over previous
//
#include <hip/hip_runtime.h>
#include <hip/hip_bf16.h>

#define HF 64
#define EPS 1e-5f

#define BSH 9                    // bucket shift: 512 nodes / bucket
#define BKN (1 << BSH)           // 512 nodes per bucket
#define NBUCK_MAX 256            // >= ceil(N / BKN)
#define PB_T 256                 // passB threads
#define PB_EPT 32                // edges per thread
#define PB_TILE (PB_T * PB_EPT)  // 8192 edges per block

#define LGRID 2048               // k_layer grid: grid-stride over nodes

typedef __hip_bfloat16 bf16;

__device__ __forceinline__ unsigned char f32_to_fp8(float v) {
    int p = __builtin_amdgcn_cvt_pk_fp8_f32(v, v, 0, false);
    return (unsigned char)(p & 0xff);
}

__device__ __forceinline__ float rdlane(float v, int k) {
    return __int_as_float(__builtin_amdgcn_readlane(__float_as_int(v), k));
}

__device__ __forceinline__ unsigned bf16_rne_hi(float x) {
    unsigned u = __float_as_uint(x);
    return (u + 0x7fffu + ((u >> 16) & 1u)) & 0xffff0000u;  // rounded, kept in high half
}

// ---- bucket histogram: LDS per-block, one global atomic per (block,bucket) ----
__global__ __launch_bounds__(PB_T) void k_bhist(const int* __restrict__ dst,
                                                int* __restrict__ bcnt, int E, int B) {
    __shared__ int bh[NBUCK_MAX];
    int t = threadIdx.x;
    for (int b = t; b < B; b += PB_T) bh[b] = 0;
    __syncthreads();
    int tile0 = blockIdx.x * PB_TILE;
#pragma unroll
    for (int k = 0; k < PB_EPT; ++k) {
        int e = tile0 + k * PB_T + t;
        if (e < E) atomicAdd(&bh[dst[e] >> BSH], 1);
    }
    __syncthreads();
    for (int b = t; b < B; b += PB_T) {
        int c = bh[b];
        if (c) atomicAdd(&bcnt[b], c);
    }
}

// ---- bucket scan: bbase2 = excl scan(bcnt); bcur = bbase2; base[N] = E ----
__global__ void k_bscan(const int* __restrict__ bcnt, int* __restrict__ bbase2,
                        int* __restrict__ bcur, int* __restrict__ base, int B, int N, int E) {
    if (threadIdx.x == 0 && blockIdx.x == 0) {
        int acc = 0;
        for (int i = 0; i < B; ++i) { bbase2[i] = acc; bcur[i] = acc; acc += bcnt[i]; }
        bbase2[B] = acc;   // == E
        base[N] = E;
    }
}

// ---- pass B: block-tiled binning; reserve per-(block,bucket) RUNS, write block-private ----
__global__ __launch_bounds__(PB_T) void k_passB(
    const int* __restrict__ src, const int* __restrict__ dst,
    int* __restrict__ bcur, int* __restrict__ stage, int E, int B) {
    __shared__ int scnt[NBUCK_MAX];
    __shared__ int sgoff[NBUCK_MAX];
    int t = threadIdx.x;
    int tile0 = blockIdx.x * PB_TILE;

    for (int b = t; b < B; b += PB_T) scnt[b] = 0;
    __syncthreads();

    int rec[PB_EPT];
    int bkt[PB_EPT];
#pragma unroll
    for (int k = 0; k < PB_EPT; ++k) {
        int e = tile0 + k * PB_T + t;
        bkt[k] = -1;
        if (e < E) {
            int d = dst[e];
            int s = src[e];
            int b = d >> BSH;
            bkt[k] = b;
            rec[k] = s | ((d & (BKN - 1)) << 17);
            atomicAdd(&scnt[b], 1);
        }
    }
    __syncthreads();

    for (int b = t; b < B; b += PB_T) {
        int c = scnt[b];
        sgoff[b] = c ? atomicAdd(&bcur[b], c) : 0;
        scnt[b] = 0;
    }
    __syncthreads();

#pragma unroll
    for (int k = 0; k < PB_EPT; ++k) {
        if (bkt[k] >= 0) {
            int loc = atomicAdd(&scnt[bkt[k]], 1);
            stage[sgoff[bkt[k]] + loc] = rec[k];
        }
    }
}

// ---- pass C: per bucket: LDS node-hist -> scan -> base/dinv -> scatter csr ----
__global__ __launch_bounds__(512) void k_passC(const int* __restrict__ stage,
                                               const int* __restrict__ bb2,
                                               int* __restrict__ base,
                                               float* __restrict__ dinv,
                                               int* __restrict__ csr, int N) {
    __shared__ int lcnt[BKN];
    __shared__ int lscan[BKN];
    __shared__ int lcur[BKN];
    int beta = blockIdx.x;
    int n0 = beta * BKN;
    int n1 = n0 + BKN; if (n1 > N) n1 = N;
    int nn = n1 - n0;
    int t = threadIdx.x;       // blockDim == 512 == BKN
    lcnt[t] = 0;
    __syncthreads();
    int rbeg = bb2[beta], rend = bb2[beta + 1];
    for (int i = rbeg + t; i < rend; i += 512)
        atomicAdd(&lcnt[stage[i] >> 17], 1);
    __syncthreads();
    int v = lcnt[t];
    lscan[t] = v;
    __syncthreads();
    for (int off = 1; off < 512; off <<= 1) {
        int val = lscan[t];
        int add = (t >= off) ? lscan[t - off] : 0;
        __syncthreads();
        lscan[t] = val + add;
        __syncthreads();
    }
    int b = rbeg + lscan[t] - v;   // exclusive scan + bucket start
    if (t < nn) {
        base[n0 + t] = b;
        dinv[n0 + t] = rsqrtf((float)v + 1.0f);
    }
    lcur[t] = b;
    __syncthreads();
    for (int i = rbeg + t; i < rend; i += 512) {
        int r = stage[i];
        int pos = atomicAdd(&lcur[r >> 17], 1);
        csr[pos] = r & 0x1ffff;
    }
}

// ---- prescale: xs[n,c] = x[n,c] * dinv[n] ----
__global__ void k_prescale(const float* __restrict__ x, const float* __restrict__ dinv,
                           float* __restrict__ xs, int N5) {
    int i = blockIdx.x * blockDim.x + threadIdx.x;
    if (i < N5) xs[i] = x[i] * dinv[i / 5];
}

// ---- layer 1 fused: multi-neighbor gather (8 neighbors / wave VMEM instr) ----
// lane = g*8 + c, g in 0..7 (neighbor slot), c in 0..7 (feature, c<5 useful).
// xs is padded, so c=5..7 over-reads are safe + discarded.
__global__ __launch_bounds__(256) void k_layer1(
    const float* __restrict__ xs, unsigned char* __restrict__ hout,
    const int* __restrict__ csr, const int* __restrict__ basep,
    const float* __restrict__ dinv,
    const float* __restrict__ W1, const float* __restrict__ b,
    const float* __restrict__ g, const float* __restrict__ be,
    const float* __restrict__ rm, const float* __restrict__ rv, int N) {
    __shared__ float sW[5 * HF];
    __shared__ float sB[HF];
    __shared__ float sScale[HF];
    if (threadIdx.x < HF) {
        int f = threadIdx.x;
        float scale = g[f] * rsqrtf(rv[f] + EPS);
        sScale[f] = scale;
        sB[f] = (b[f] - rm[f]) * scale + be[f];
    }
    __syncthreads();
    for (int i = threadIdx.x; i < 5 * HF; i += blockDim.x)
        sW[i] = W1[i] * sScale[i & (HF - 1)];
    __syncthreads();

    int lane = threadIdx.x & 63;
    int wave = threadIdx.x >> 6;
    int c  = lane & 7;     // feature (c<5 useful)
    int g8 = lane >> 3;    // neighbor slot 0..7
    int stride = gridDim.x * 4;

    for (int node = blockIdx.x * 4 + wave; node < N; node += stride) {
        int j   = __builtin_amdgcn_readfirstlane(basep[node]);
        int end = __builtin_amdgcn_readfirstlane(basep[node + 1]);

        // self term: slot 0 only (counted once after the cross-slot reduction)
        float a0 = 0.f, a1 = 0.f, a2 = 0.f, a3 = 0.f;
        if (g8 == 0 && c < 5) a0 = xs[node * 5 + c];

        // 32 neighbors / iteration: 4 vector csr loads + 4 gathers in flight
        for (; j + 32 <= end; j += 32) {
            int s0 = csr[j + g8];
            int s1 = csr[j + 8 + g8];
            int s2 = csr[j + 16 + g8];
            int s3 = csr[j + 24 + g8];
            float v0 = xs[s0 * 5 + c];   // c>=5 lanes read pad garbage; discarded below
            float v1 = xs[s1 * 5 + c];
            float v2 = xs[s2 * 5 + c];
            float v3 = xs[s3 * 5 + c];
            a0 += v0; a1 += v1; a2 += v2; a3 += v3;
        }
        for (; j + 8 <= end; j += 8) {
            int s = csr[j + g8];
            a0 += xs[s * 5 + c];
        }
        if (j < end) {                    // tail <8: slot g8 takes neighbor j+g8
            if (j + g8 < end) {
                int s = csr[j + g8];
                a0 += xs[s * 5 + c];
            }
        }

        // fold the 8 neighbor slots: xor over g bits (3,4,5)
        float acc = (a0 + a1) + (a2 + a3);
        acc += __shfl_xor(acc, 8, 64);
        acc += __shfl_xor(acc, 16, 64);
        acc += __shfl_xor(acc, 32, 64);

        float di = dinv[node];
        acc *= di;

        float out = sB[lane];
#pragma unroll
        for (int k = 0; k < 5; ++k) out += __shfl(acc, k, 64) * sW[k * HF + lane];
        out = fmaxf(out, 0.f);
        hout[(size_t)node * HF + lane] = f32_to_fp8(out * di);  // pre-scale for next layer
    }
}

// ---- layers 2/3 fused: byte-gather + bf16-PACKED register weights + readlane MLP ----
// wp[32] (2xbf16/dword) + 16 in-flight gather bytes + temps ~= 90 VGPR.
// __launch_bounds__(256,4): VGPR cap 128 -> NO SPILL (cap 85 at (256,6) spilled wp
// to scratch: VGPR 40, FETCH 112->359MB, 97->180us. Spill is worse than low occ.)
// SCALE_OUT=1: write fp8 hs = h*dinv. SCALE_OUT=0: write fp32 h (feeds pool).
template <int SCALE_OUT>
__global__ __launch_bounds__(256, 4) void k_layer(
    const unsigned char* __restrict__ hs8, void* __restrict__ hout_v,
    const int* __restrict__ csr, const int* __restrict__ basep,
    const float* __restrict__ dinv,
    const float* __restrict__ W, const float* __restrict__ b,
    const float* __restrict__ g, const float* __restrict__ be,
    const float* __restrict__ rm, const float* __restrict__ rv, int N) {
    int lane = threadIdx.x & 63;
    int wave = threadIdx.x >> 6;
    int stride = gridDim.x * 4;
    const unsigned char* col = hs8 + lane;   // lane's feature column

    // fold BN into per-lane scale/bias; pack weight column as bf16 pairs
    float scale = g[lane] * rsqrtf(rv[lane] + EPS);
    float bias  = (b[lane] - rm[lane]) * scale + be[lane];
    unsigned wp[HF / 2];
#pragma unroll
    for (int k2 = 0; k2 < HF / 2; ++k2) {
        unsigned lo = bf16_rne_hi(W[(2 * k2 + 0) * HF + lane] * scale);
        unsigned hi = bf16_rne_hi(W[(2 * k2 + 1) * HF + lane] * scale);
        wp[k2] = (lo >> 16) | hi;
    }

    for (int node = blockIdx.x * 4 + wave; node < N; node += stride) {
        int j   = __builtin_amdgcn_readfirstlane(basep[node]);
        int end = __builtin_amdgcn_readfirstlane(basep[node + 1]);

        // self term (already *dinv[src])
        float a0 = __builtin_amdgcn_cvt_f32_fp8((unsigned)col[(size_t)node * HF], 0);
        float a1 = 0.f, a2 = 0.f, a3 = 0.f;

        // 16-wide: 16 scalar csr loads (wave-uniform j -> s_load) then 16
        // independent coalesced byte-gathers all in flight before first use
        for (; j + 16 <= end; j += 16) {
            int s0 = csr[j+0],  s1 = csr[j+1],  s2 = csr[j+2],  s3 = csr[j+3];
            int s4 = csr[j+4],  s5 = csr[j+5],  s6 = csr[j+6],  s7 = csr[j+7];
            int s8 = csr[j+8],  s9 = csr[j+9],  sA = csr[j+10], sB_ = csr[j+11];
            int sC = csr[j+12], sD = csr[j+13], sE = csr[j+14], sF = csr[j+15];
            unsigned u0 = col[(size_t)s0 * HF];
            unsigned u1 = col[(size_t)s1 * HF];
            unsigned u2 = col[(size_t)s2 * HF];
            unsigned u3 = col[(size_t)s3 * HF];
            unsigned u4 = col[(size_t)s4 * HF];
            unsigned u5 = col[(size_t)s5 * HF];
            unsigned u6 = col[(size_t)s6 * HF];
            unsigned u7 = col[(size_t)s7 * HF];
            unsigned u8 = col[(size_t)s8 * HF];
            unsigned u9 = col[(size_t)s9 * HF];
            unsigned uA = col[(size_t)sA * HF];
            unsigned uB = col[(size_t)sB_ * HF];
            unsigned uC = col[(size_t)sC * HF];
            unsigned uD = col[(size_t)sD * HF];
            unsigned uE = col[(size_t)sE * HF];
            unsigned uF = col[(size_t)sF * HF];
            a0 += __builtin_amdgcn_cvt_f32_fp8(u0, 0);
            a1 += __builtin_amdgcn_cvt_f32_fp8(u1, 0);
            a2 += __builtin_amdgcn_cvt_f32_fp8(u2, 0);
            a3 += __builtin_amdgcn_cvt_f32_fp8(u3, 0);
            a0 += __builtin_amdgcn_cvt_f32_fp8(u4, 0);
            a1 += __builtin_amdgcn_cvt_f32_fp8(u5, 0);
            a2 += __builtin_amdgcn_cvt_f32_fp8(u6, 0);
            a3 += __builtin_amdgcn_cvt_f32_fp8(u7, 0);
            a0 += __builtin_amdgcn_cvt_f32_fp8(u8, 0);
            a1 += __builtin_amdgcn_cvt_f32_fp8(u9, 0);
            a2 += __builtin_amdgcn_cvt_f32_fp8(uA, 0);
            a3 += __builtin_amdgcn_cvt_f32_fp8(uB, 0);
            a0 += __builtin_amdgcn_cvt_f32_fp8(uC, 0);
            a1 += __builtin_amdgcn_cvt_f32_fp8(uD, 0);
            a2 += __builtin_amdgcn_cvt_f32_fp8(uE, 0);
            a3 += __builtin_amdgcn_cvt_f32_fp8(uF, 0);
        }
        for (; j + 4 <= end; j += 4) {
            int s0 = csr[j+0], s1 = csr[j+1], s2 = csr[j+2], s3 = csr[j+3];
            unsigned u0 = col[(size_t)s0 * HF];
            unsigned u1 = col[(size_t)s1 * HF];
            unsigned u2 = col[(size_t)s2 * HF];
            unsigned u3 = col[(size_t)s3 * HF];
            a0 += __builtin_amdgcn_cvt_f32_fp8(u0, 0);
            a1 += __builtin_amdgcn_cvt_f32_fp8(u1, 0);
            a2 += __builtin_amdgcn_cvt_f32_fp8(u2, 0);
            a3 += __builtin_amdgcn_cvt_f32_fp8(u3, 0);
        }
        for (; j < end; ++j) {
            int s = csr[j];
            a0 += __builtin_amdgcn_cvt_f32_fp8((unsigned)col[(size_t)s * HF], 0);
        }
        float di = dinv[node];
        float acc = ((a0 + a1) + (a2 + a3)) * di;

        // readlane MLP against packed bf16 register weights (no memory traffic).
        float o0 = bias, o1 = 0.f, o2 = 0.f, o3 = 0.f;
#pragma unroll
        for (int k = 0; k < HF; k += 4) {
            unsigned pA = wp[k / 2 + 0];
            unsigned pB = wp[k / 2 + 1];
            o0 += rdlane(acc, k + 0) * __uint_as_float(pA << 16);
            o1 += rdlane(acc, k + 1) * __uint_as_float(pA & 0xffff0000u);
            o2 += rdlane(acc, k + 2) * __uint_as_float(pB << 16);
            o3 += rdlane(acc, k + 3) * __uint_as_float(pB & 0xffff0000u);
        }
        float out = fmaxf((o0 + o1) + (o2 + o3), 0.f);
        if (SCALE_OUT) {
            ((unsigned char*)hout_v)[(size_t)node * HF + lane] = f32_to_fp8(out * di);
        } else {
            ((float*)hout_v)[(size_t)node * HF + lane] = out;
        }
    }
}

// ---- per-graph mean-pool + FC(64->32) relu + FC(32->2) sigmoid ----
__global__ void k_pool_fc(const float* __restrict__ h, const int* __restrict__ batch,
                          const float* __restrict__ Wf1, const float* __restrict__ bf1,
                          const float* __restrict__ Wf2, const float* __restrict__ bf2,
                          float* __restrict__ out, int N) {
    int g = blockIdx.x;
    int t = threadIdx.x;
    int f = t & 63, q = t >> 6;

    int lo = 0, hi = N;
    while (lo < hi) { int mid = (lo + hi) >> 1; if (batch[mid] < g) lo = mid + 1; else hi = mid; }
    int start = lo;
    hi = N;
    while (lo < hi) { int mid = (lo + hi) >> 1; if (batch[mid] < g + 1) lo = mid + 1; else hi = mid; }
    int end = lo;

    float sum = 0.f;
    for (int n = start + q; n < end; n += 4) sum += h[n * HF + f];

    __shared__ float red[4][HF];
    __shared__ float sp[HF];
    __shared__ float sh[32];
    red[q][f] = sum;
    __syncthreads();
    if (q == 0) {
        float s = red[0][f] + red[1][f] + red[2][f] + red[3][f];
        float cntf = (float)(end - start);
        sp[f] = s / fmaxf(cntf, 1.0f);
    }
    __syncthreads();
    if (t < 32) {
        float a = bf1[t];
#pragma unroll
        for (int k = 0; k < HF; ++k) a += sp[k] * Wf1[k * 32 + t];
        sh[t] = fmaxf(a, 0.f);
    }
    __syncthreads();
    if (t < 2) {
        float a = bf2[t];
#pragma unroll
        for (int k = 0; k < 32; ++k) a += sh[k] * Wf2[k * 2 + t];
        out[g * 2 + t] = 1.f / (1.f + expf(-a));
    }
}

extern "C" void kernel_launch(void* const* d_in, const int* in_sizes, int n_in,
                              void* d_out, int out_size, void* d_ws, size_t ws_size,
                              hipStream_t stream) {
    const float* x     = (const float*)d_in[0];
    const int*   ei    = (const int*)d_in[1];
    const int*   batch = (const int*)d_in[2];
    const float* W1 = (const float*)d_in[3];
    const float* b1 = (const float*)d_in[4];
    const float* g1 = (const float*)d_in[5];
    const float* be1 = (const float*)d_in[6];
    const float* rm1 = (const float*)d_in[7];
    const float* rv1 = (const float*)d_in[8];
    const float* W2 = (const float*)d_in[9];
    const float* b2 = (const float*)d_in[10];
    const float* g2 = (const float*)d_in[11];
    const float* be2 = (const float*)d_in[12];
    const float* rm2 = (const float*)d_in[13];
    const float* rv2 = (const float*)d_in[14];
    const float* W3 = (const float*)d_in[15];
    const float* b3 = (const float*)d_in[16];
    const float* g3 = (const float*)d_in[17];
    const float* be3 = (const float*)d_in[18];
    const float* rm3 = (const float*)d_in[19];
    const float* rv3 = (const float*)d_in[20];
    const float* Wf1 = (const float*)d_in[21];
    const float* bf1 = (const float*)d_in[22];
    const float* Wf2 = (const float*)d_in[23];
    const float* bf2 = (const float*)d_in[24];
    float* out = (float*)d_out;

    const int N = in_sizes[2];            // 100000
    const int E = in_sizes[1] / 2;        // 3200000
    const int G = out_size / 2;           // 256
    const int B = (N + BKN - 1) / BKN;    // buckets (196)

    char* ws = (char*)d_ws;
    size_t off = 0;
    auto alloc = [&](size_t bytes) {
        char* p = ws + off;
        off += (bytes + 255) & ~(size_t)255;
        return p;
    };
    float*         H3       = (float*)alloc((size_t)N * HF * sizeof(float));
    unsigned char* HS1      = (unsigned char*)alloc((size_t)N * HF);
    unsigned char* HS2      = (unsigned char*)alloc((size_t)N * HF);
    float*         xs       = (float*)alloc((size_t)N * 5 * sizeof(float) + 64);  // +pad: c=5..7 over-read
    float*         dinv     = (float*)alloc((size_t)N * sizeof(float));
    int*           base     = (int*)  alloc(((size_t)N + 1) * sizeof(int));
    int*           bcnt     = (int*)  alloc((size_t)NBUCK_MAX * sizeof(int));
    int*           bbase2   = (int*)  alloc(((size_t)NBUCK_MAX + 1) * sizeof(int));
    int*           bcur     = (int*)  alloc((size_t)NBUCK_MAX * sizeof(int));
    int*           csr      = (int*)  alloc((size_t)E * sizeof(int));
    int*           stage    = (int*)H3;   // alias: consumed (passC) before H3 written (layer 3)

    const int* src = ei;
    const int* dst = ei + E;

    const int BT = 256;
    int gP  = (N * 5 + BT - 1) / BT;
    int gPB = (E + PB_TILE - 1) / PB_TILE;

    // ---- CSR build: bucket hist -> 196-scan -> run-reserving partition -> local scatter ----
    hipMemsetAsync(bcnt, 0, (size_t)B * sizeof(int), stream);
    k_bhist<<<gPB, PB_T, 0, stream>>>(dst, bcnt, E, B);
    k_bscan<<<1, 64, 0, stream>>>(bcnt, bbase2, bcur, base, B, N, E);
    k_passB<<<gPB, PB_T, 0, stream>>>(src, dst, bcur, stage, E, B);
    k_passC<<<B, 512, 0, stream>>>(stage, bbase2, base, dinv, csr, N);
    k_prescale<<<gP, BT, 0, stream>>>(x, dinv, xs, N * 5);

    // ---- fused layers (weights in registers; grid-stride over nodes) ----
    k_layer1<<<LGRID, BT, 0, stream>>>(xs, HS1, csr, base, dinv,
                                       W1, b1, g1, be1, rm1, rv1, N);
    k_layer<1><<<LGRID, BT, 0, stream>>>(HS1, HS2, csr, base, dinv,
                                         W2, b2, g2, be2, rm2, rv2, N);
    k_layer<0><<<LGRID, BT, 0, stream>>>(HS2, H3, csr, base, dinv,
                                         W3, b3, g3, be3, rm3, rv3, N);

    // ---- pool + MLP head ----
    k_pool_fc<<<G, BT, 0, stream>>>(H3, batch, Wf1, bf1, Wf2, bf2, out, N);
}

// Round 6
// 427.508 us; speedup vs baseline: 1.4425x; 1.0750x over previous
//
#include <hip/hip_runtime.h>
#include <hip/hip_bf16.h>

#define HF 64
#define EPS 1e-5f

#define BSH 9                    // bucket shift: 512 nodes / bucket
#define BKN (1 << BSH)           // 512 nodes per bucket
#define NBUCK_MAX 256            // >= ceil(N / BKN)
#define PB_T 256                 // passB threads
#define PB_EPT 32                // edges per thread
#define PB_TILE (PB_T * PB_EPT)  // 8192 edges per block

#define LGRID 2048               // k_layer grid: grid-stride over nodes

typedef __hip_bfloat16 bf16;

__device__ __forceinline__ unsigned char f32_to_fp8(float v) {
    int p = __builtin_amdgcn_cvt_pk_fp8_f32(v, v, 0, false);
    return (unsigned char)(p & 0xff);
}

__device__ __forceinline__ float rdlane(float v, int k) {
    return __int_as_float(__builtin_amdgcn_readlane(__float_as_int(v), k));
}

__device__ __forceinline__ unsigned bf16_rne_hi(float x) {
    unsigned u = __float_as_uint(x);
    return (u + 0x7fffu + ((u >> 16) & 1u)) & 0xffff0000u;  // rounded, kept in high half
}

// ---- bucket histogram: LDS per-block, one global atomic per (block,bucket) ----
__global__ __launch_bounds__(PB_T) void k_bhist(const int* __restrict__ dst,
                                                int* __restrict__ bcnt, int E, int B) {
    __shared__ int bh[NBUCK_MAX];
    int t = threadIdx.x;
    for (int b = t; b < B; b += PB_T) bh[b] = 0;
    __syncthreads();
    int tile0 = blockIdx.x * PB_TILE;
#pragma unroll
    for (int k = 0; k < PB_EPT; ++k) {
        int e = tile0 + k * PB_T + t;
        if (e < E) atomicAdd(&bh[dst[e] >> BSH], 1);
    }
    __syncthreads();
    for (int b = t; b < B; b += PB_T) {
        int c = bh[b];
        if (c) atomicAdd(&bcnt[b], c);
    }
}

// ---- bucket scan: bbase2 = excl scan(bcnt); bcur = bbase2; base[N] = E ----
__global__ void k_bscan(const int* __restrict__ bcnt, int* __restrict__ bbase2,
                        int* __restrict__ bcur, int* __restrict__ base, int B, int N, int E) {
    if (threadIdx.x == 0 && blockIdx.x == 0) {
        int acc = 0;
        for (int i = 0; i < B; ++i) { bbase2[i] = acc; bcur[i] = acc; acc += bcnt[i]; }
        bbase2[B] = acc;   // == E
        base[N] = E;
    }
}

// ---- pass B: block-tiled binning; reserve per-(block,bucket) RUNS, write block-private ----
__global__ __launch_bounds__(PB_T) void k_passB(
    const int* __restrict__ src, const int* __restrict__ dst,
    int* __restrict__ bcur, int* __restrict__ stage, int E, int B) {
    __shared__ int scnt[NBUCK_MAX];
    __shared__ int sgoff[NBUCK_MAX];
    int t = threadIdx.x;
    int tile0 = blockIdx.x * PB_TILE;

    for (int b = t; b < B; b += PB_T) scnt[b] = 0;
    __syncthreads();

    int rec[PB_EPT];
    int bkt[PB_EPT];
#pragma unroll
    for (int k = 0; k < PB_EPT; ++k) {
        int e = tile0 + k * PB_T + t;
        bkt[k] = -1;
        if (e < E) {
            int d = dst[e];
            int s = src[e];
            int b = d >> BSH;
            bkt[k] = b;
            rec[k] = s | ((d & (BKN - 1)) << 17);
            atomicAdd(&scnt[b], 1);
        }
    }
    __syncthreads();

    for (int b = t; b < B; b += PB_T) {
        int c = scnt[b];
        sgoff[b] = c ? atomicAdd(&bcur[b], c) : 0;
        scnt[b] = 0;
    }
    __syncthreads();

#pragma unroll
    for (int k = 0; k < PB_EPT; ++k) {
        if (bkt[k] >= 0) {
            int loc = atomicAdd(&scnt[bkt[k]], 1);
            stage[sgoff[bkt[k]] + loc] = rec[k];
        }
    }
}

// ---- pass C: per bucket: LDS node-hist -> scan -> base/dinv -> scatter csr ----
__global__ __launch_bounds__(512) void k_passC(const int* __restrict__ stage,
                                               const int* __restrict__ bb2,
                                               int* __restrict__ base,
                                               float* __restrict__ dinv,
                                               int* __restrict__ csr, int N) {
    __shared__ int lcnt[BKN];
    __shared__ int lscan[BKN];
    __shared__ int lcur[BKN];
    int beta = blockIdx.x;
    int n0 = beta * BKN;
    int n1 = n0 + BKN; if (n1 > N) n1 = N;
    int nn = n1 - n0;
    int t = threadIdx.x;       // blockDim == 512 == BKN
    lcnt[t] = 0;
    __syncthreads();
    int rbeg = bb2[beta], rend = bb2[beta + 1];
    for (int i = rbeg + t; i < rend; i += 512)
        atomicAdd(&lcnt[stage[i] >> 17], 1);
    __syncthreads();
    int v = lcnt[t];
    lscan[t] = v;
    __syncthreads();
    for (int off = 1; off < 512; off <<= 1) {
        int val = lscan[t];
        int add = (t >= off) ? lscan[t - off] : 0;
        __syncthreads();
        lscan[t] = val + add;
        __syncthreads();
    }
    int b = rbeg + lscan[t] - v;   // exclusive scan + bucket start
    if (t < nn) {
        base[n0 + t] = b;
        dinv[n0 + t] = rsqrtf((float)v + 1.0f);
    }
    lcur[t] = b;
    __syncthreads();
    for (int i = rbeg + t; i < rend; i += 512) {
        int r = stage[i];
        int pos = atomicAdd(&lcur[r >> 17], 1);
        csr[pos] = r & 0x1ffff;
    }
}

// ---- prescale: xs[n,c] = x[n,c] * dinv[n] ----
__global__ void k_prescale(const float* __restrict__ x, const float* __restrict__ dinv,
                           float* __restrict__ xs, int N5) {
    int i = blockIdx.x * blockDim.x + threadIdx.x;
    if (i < N5) xs[i] = x[i] * dinv[i / 5];
}

// ---- layer 1 fused: multi-neighbor gather (8 neighbors / wave VMEM instr) ----
// lane = g*8 + c, g in 0..7 (neighbor slot), c in 0..7 (feature, c<5 useful).
// xs is padded, so c=5..7 over-reads are safe + discarded.
__global__ __launch_bounds__(256) void k_layer1(
    const float* __restrict__ xs, unsigned char* __restrict__ hout,
    const int* __restrict__ csr, const int* __restrict__ basep,
    const float* __restrict__ dinv,
    const float* __restrict__ W1, const float* __restrict__ b,
    const float* __restrict__ g, const float* __restrict__ be,
    const float* __restrict__ rm, const float* __restrict__ rv, int N) {
    __shared__ float sW[5 * HF];
    __shared__ float sB[HF];
    __shared__ float sScale[HF];
    if (threadIdx.x < HF) {
        int f = threadIdx.x;
        float scale = g[f] * rsqrtf(rv[f] + EPS);
        sScale[f] = scale;
        sB[f] = (b[f] - rm[f]) * scale + be[f];
    }
    __syncthreads();
    for (int i = threadIdx.x; i < 5 * HF; i += blockDim.x)
        sW[i] = W1[i] * sScale[i & (HF - 1)];
    __syncthreads();

    int lane = threadIdx.x & 63;
    int wave = threadIdx.x >> 6;
    int c  = lane & 7;     // feature (c<5 useful)
    int g8 = lane >> 3;    // neighbor slot 0..7
    int stride = gridDim.x * 4;

    for (int node = blockIdx.x * 4 + wave; node < N; node += stride) {
        int j   = __builtin_amdgcn_readfirstlane(basep[node]);
        int end = __builtin_amdgcn_readfirstlane(basep[node + 1]);

        // self term: slot 0 only (counted once after the cross-slot reduction)
        float a0 = 0.f, a1 = 0.f, a2 = 0.f, a3 = 0.f;
        if (g8 == 0 && c < 5) a0 = xs[node * 5 + c];

        // 32 neighbors / iteration: 4 vector csr loads + 4 gathers in flight
        for (; j + 32 <= end; j += 32) {
            int s0 = csr[j + g8];
            int s1 = csr[j + 8 + g8];
            int s2 = csr[j + 16 + g8];
            int s3 = csr[j + 24 + g8];
            float v0 = xs[s0 * 5 + c];   // c>=5 lanes read pad garbage; discarded below
            float v1 = xs[s1 * 5 + c];
            float v2 = xs[s2 * 5 + c];
            float v3 = xs[s3 * 5 + c];
            a0 += v0; a1 += v1; a2 += v2; a3 += v3;
        }
        for (; j + 8 <= end; j += 8) {
            int s = csr[j + g8];
            a0 += xs[s * 5 + c];
        }
        if (j < end) {                    // tail <8: slot g8 takes neighbor j+g8
            if (j + g8 < end) {
                int s = csr[j + g8];
                a0 += xs[s * 5 + c];
            }
        }

        // fold the 8 neighbor slots: xor over g bits (3,4,5)
        float acc = (a0 + a1) + (a2 + a3);
        acc += __shfl_xor(acc, 8, 64);
        acc += __shfl_xor(acc, 16, 64);
        acc += __shfl_xor(acc, 32, 64);

        float di = dinv[node];
        acc *= di;

        float out = sB[lane];
#pragma unroll
        for (int k = 0; k < 5; ++k) out += __shfl(acc, k, 64) * sW[k * HF + lane];
        out = fmaxf(out, 0.f);
        hout[(size_t)node * HF + lane] = f32_to_fp8(out * di);  // pre-scale for next layer
    }
}

// ---- layers 2/3 fused: pipelined byte-gather + LDS bf16 weights + readlane MLP ----
// Never let the wave's vmcnt queue drain:
//  * gather windows of 8, double-buffered (consume u while v flies -> counted vmcnt)
//  * previous node's MLP+store runs while current node's first window is in flight
//  * MLP is vmcnt-FREE: weights in LDS (bf16-packed, XOR-swizzled [64][8] uint4,
//    conflict-free ds_read_b128 on the lgkm counter) + readlane broadcast (VALU).
// SCALE_OUT=1: write fp8 hs = h*dinv. SCALE_OUT=0: write fp32 h (feeds pool).
template <int SCALE_OUT>
__global__ __launch_bounds__(256, 4) void k_layer(
    const unsigned char* __restrict__ hs8, void* __restrict__ hout_v,
    const int* __restrict__ csr, const int* __restrict__ basep,
    const float* __restrict__ dinv,
    const float* __restrict__ W, const float* __restrict__ b,
    const float* __restrict__ g, const float* __restrict__ be,
    const float* __restrict__ rm, const float* __restrict__ rv, int N) {
    __shared__ uint4 swp4[64][8];   // [col][slot] slot = chunk ^ (col&7); 8 KB

    int lane = threadIdx.x & 63;
    int wave = threadIdx.x >> 6;
    int stride = gridDim.x * 4;
    const unsigned char* col = hs8 + lane;   // lane's feature column

    // stage bf16-packed, BN-folded weight columns once per block
    if (threadIdx.x < 64) {
        int l = threadIdx.x;
        float sc = g[l] * rsqrtf(rv[l] + EPS);
#pragma unroll
        for (int c = 0; c < 8; ++c) {
            unsigned p[4];
#pragma unroll
            for (int q = 0; q < 4; ++q) {
                int k2 = c * 4 + q;
                unsigned lo = bf16_rne_hi(W[(2 * k2 + 0) * HF + l] * sc);
                unsigned hi = bf16_rne_hi(W[(2 * k2 + 1) * HF + l] * sc);
                p[q] = (lo >> 16) | hi;
            }
            swp4[l][c ^ (l & 7)] = make_uint4(p[0], p[1], p[2], p[3]);
        }
    }
    __syncthreads();

    float scale = g[lane] * rsqrtf(rv[lane] + EPS);
    float bias  = (b[lane] - rm[lane]) * scale + be[lane];

    auto mlp_store = [&](float acc, int nodeS, float diS) {
        float o0 = bias, o1 = 0.f, o2 = 0.f, o3 = 0.f;
#pragma unroll
        for (int c = 0; c < 8; ++c) {
            uint4 pv = swp4[lane][c ^ (lane & 7)];
            int k0 = c * 8;
            o0 += rdlane(acc, k0 + 0) * __uint_as_float(pv.x << 16);
            o1 += rdlane(acc, k0 + 1) * __uint_as_float(pv.x & 0xffff0000u);
            o2 += rdlane(acc, k0 + 2) * __uint_as_float(pv.y << 16);
            o3 += rdlane(acc, k0 + 3) * __uint_as_float(pv.y & 0xffff0000u);
            o0 += rdlane(acc, k0 + 4) * __uint_as_float(pv.z << 16);
            o1 += rdlane(acc, k0 + 5) * __uint_as_float(pv.z & 0xffff0000u);
            o2 += rdlane(acc, k0 + 6) * __uint_as_float(pv.w << 16);
            o3 += rdlane(acc, k0 + 7) * __uint_as_float(pv.w & 0xffff0000u);
        }
        float out = fmaxf((o0 + o1) + (o2 + o3), 0.f);
        if (SCALE_OUT) {
            ((unsigned char*)hout_v)[(size_t)nodeS * HF + lane] = f32_to_fp8(out * diS);
        } else {
            ((float*)hout_v)[(size_t)nodeS * HF + lane] = out;
        }
    };

    float accP = 0.f, diP = 0.f;
    int nodeP = -1;

    for (int node = blockIdx.x * 4 + wave; node < N; node += stride) {
        int j   = __builtin_amdgcn_readfirstlane(basep[node]);
        int end = __builtin_amdgcn_readfirstlane(basep[node + 1]);

        // self term (already *dinv[src])
        float a0 = __builtin_amdgcn_cvt_f32_fp8((unsigned)col[(size_t)node * HF], 0);
        float a1 = 0.f, a2 = 0.f, a3 = 0.f;

        // issue first 8-window BEFORE prev node's MLP -> loads fly under the MLP
        unsigned u0 = 0, u1 = 0, u2 = 0, u3 = 0, u4 = 0, u5 = 0, u6 = 0, u7 = 0;
        bool w0 = (j + 8 <= end);
        if (w0) {
            int s0 = csr[j+0], s1 = csr[j+1], s2 = csr[j+2], s3 = csr[j+3];
            int s4 = csr[j+4], s5 = csr[j+5], s6 = csr[j+6], s7 = csr[j+7];
            u0 = col[(size_t)s0 * HF]; u1 = col[(size_t)s1 * HF];
            u2 = col[(size_t)s2 * HF]; u3 = col[(size_t)s3 * HF];
            u4 = col[(size_t)s4 * HF]; u5 = col[(size_t)s5 * HF];
            u6 = col[(size_t)s6 * HF]; u7 = col[(size_t)s7 * HF];
        }

        // previous node's MLP + store (vmcnt-free: LDS + readlane + VALU only)
        if (nodeP >= 0) mlp_store(accP, nodeP, diP);

        if (w0) {
            j += 8;
            // steady state: issue window v while consuming window u (vmcnt(8)-counted)
            while (j + 8 <= end) {
                int t0 = csr[j+0], t1 = csr[j+1], t2 = csr[j+2], t3 = csr[j+3];
                int t4 = csr[j+4], t5 = csr[j+5], t6 = csr[j+6], t7 = csr[j+7];
                unsigned v0 = col[(size_t)t0 * HF];
                unsigned v1 = col[(size_t)t1 * HF];
                unsigned v2 = col[(size_t)t2 * HF];
                unsigned v3 = col[(size_t)t3 * HF];
                unsigned v4 = col[(size_t)t4 * HF];
                unsigned v5 = col[(size_t)t5 * HF];
                unsigned v6 = col[(size_t)t6 * HF];
                unsigned v7 = col[(size_t)t7 * HF];
                a0 += __builtin_amdgcn_cvt_f32_fp8(u0, 0);
                a1 += __builtin_amdgcn_cvt_f32_fp8(u1, 0);
                a2 += __builtin_amdgcn_cvt_f32_fp8(u2, 0);
                a3 += __builtin_amdgcn_cvt_f32_fp8(u3, 0);
                a0 += __builtin_amdgcn_cvt_f32_fp8(u4, 0);
                a1 += __builtin_amdgcn_cvt_f32_fp8(u5, 0);
                a2 += __builtin_amdgcn_cvt_f32_fp8(u6, 0);
                a3 += __builtin_amdgcn_cvt_f32_fp8(u7, 0);
                u0 = v0; u1 = v1; u2 = v2; u3 = v3;
                u4 = v4; u5 = v5; u6 = v6; u7 = v7;
                j += 8;
            }
            // drain final window
            a0 += __builtin_amdgcn_cvt_f32_fp8(u0, 0);
            a1 += __builtin_amdgcn_cvt_f32_fp8(u1, 0);
            a2 += __builtin_amdgcn_cvt_f32_fp8(u2, 0);
            a3 += __builtin_amdgcn_cvt_f32_fp8(u3, 0);
            a0 += __builtin_amdgcn_cvt_f32_fp8(u4, 0);
            a1 += __builtin_amdgcn_cvt_f32_fp8(u5, 0);
            a2 += __builtin_amdgcn_cvt_f32_fp8(u6, 0);
            a3 += __builtin_amdgcn_cvt_f32_fp8(u7, 0);
        }
        // tail < 8
        for (; j < end; ++j) {
            int s = csr[j];
            a0 += __builtin_amdgcn_cvt_f32_fp8((unsigned)col[(size_t)s * HF], 0);
        }

        float di = dinv[node];
        accP = ((a0 + a1) + (a2 + a3)) * di;
        diP = di;
        nodeP = node;
    }
    if (nodeP >= 0) mlp_store(accP, nodeP, diP);
}

// ---- per-graph mean-pool + FC(64->32) relu + FC(32->2) sigmoid ----
__global__ void k_pool_fc(const float* __restrict__ h, const int* __restrict__ batch,
                          const float* __restrict__ Wf1, const float* __restrict__ bf1,
                          const float* __restrict__ Wf2, const float* __restrict__ bf2,
                          float* __restrict__ out, int N) {
    int g = blockIdx.x;
    int t = threadIdx.x;
    int f = t & 63, q = t >> 6;

    int lo = 0, hi = N;
    while (lo < hi) { int mid = (lo + hi) >> 1; if (batch[mid] < g) lo = mid + 1; else hi = mid; }
    int start = lo;
    hi = N;
    while (lo < hi) { int mid = (lo + hi) >> 1; if (batch[mid] < g + 1) lo = mid + 1; else hi = mid; }
    int end = lo;

    float sum = 0.f;
    for (int n = start + q; n < end; n += 4) sum += h[n * HF + f];

    __shared__ float red[4][HF];
    __shared__ float sp[HF];
    __shared__ float sh[32];
    red[q][f] = sum;
    __syncthreads();
    if (q == 0) {
        float s = red[0][f] + red[1][f] + red[2][f] + red[3][f];
        float cntf = (float)(end - start);
        sp[f] = s / fmaxf(cntf, 1.0f);
    }
    __syncthreads();
    if (t < 32) {
        float a = bf1[t];
#pragma unroll
        for (int k = 0; k < HF; ++k) a += sp[k] * Wf1[k * 32 + t];
        sh[t] = fmaxf(a, 0.f);
    }
    __syncthreads();
    if (t < 2) {
        float a = bf2[t];
#pragma unroll
        for (int k = 0; k < 32; ++k) a += sh[k] * Wf2[k * 2 + t];
        out[g * 2 + t] = 1.f / (1.f + expf(-a));
    }
}

extern "C" void kernel_launch(void* const* d_in, const int* in_sizes, int n_in,
                              void* d_out, int out_size, void* d_ws, size_t ws_size,
                              hipStream_t stream) {
    const float* x     = (const float*)d_in[0];
    const int*   ei    = (const int*)d_in[1];
    const int*   batch = (const int*)d_in[2];
    const float* W1 = (const float*)d_in[3];
    const float* b1 = (const float*)d_in[4];
    const float* g1 = (const float*)d_in[5];
    const float* be1 = (const float*)d_in[6];
    const float* rm1 = (const float*)d_in[7];
    const float* rv1 = (const float*)d_in[8];
    const float* W2 = (const float*)d_in[9];
    const float* b2 = (const float*)d_in[10];
    const float* g2 = (const float*)d_in[11];
    const float* be2 = (const float*)d_in[12];
    const float* rm2 = (const float*)d_in[13];
    const float* rv2 = (const float*)d_in[14];
    const float* W3 = (const float*)d_in[15];
    const float* b3 = (const float*)d_in[16];
    const float* g3 = (const float*)d_in[17];
    const float* be3 = (const float*)d_in[18];
    const float* rm3 = (const float*)d_in[19];
    const float* rv3 = (const float*)d_in[20];
    const float* Wf1 = (const float*)d_in[21];
    const float* bf1 = (const float*)d_in[22];
    const float* Wf2 = (const float*)d_in[23];
    const float* bf2 = (const float*)d_in[24];
    float* out = (float*)d_out;

    const int N = in_sizes[2];            // 100000
    const int E = in_sizes[1] / 2;        // 3200000
    const int G = out_size / 2;           // 256
    const int B = (N + BKN - 1) / BKN;    // buckets (196)

    char* ws = (char*)d_ws;
    size_t off = 0;
    auto alloc = [&](size_t bytes) {
        char* p = ws + off;
        off += (bytes + 255) & ~(size_t)255;
        return p;
    };
    float*         H3       = (float*)alloc((size_t)N * HF * sizeof(float));
    unsigned char* HS1      = (unsigned char*)alloc((size_t)N * HF);
    unsigned char* HS2      = (unsigned char*)alloc((size_t)N * HF);
    float*         xs       = (float*)alloc((size_t)N * 5 * sizeof(float) + 64);  // +pad: c=5..7 over-read
    float*         dinv     = (float*)alloc((size_t)N * sizeof(float));
    int*           base     = (int*)  alloc(((size_t)N + 1) * sizeof(int));
    int*           bcnt     = (int*)  alloc((size_t)NBUCK_MAX * sizeof(int));
    int*           bbase2   = (int*)  alloc(((size_t)NBUCK_MAX + 1) * sizeof(int));
    int*           bcur     = (int*)  alloc((size_t)NBUCK_MAX * sizeof(int));
    int*           csr      = (int*)  alloc((size_t)E * sizeof(int));
    int*           stage    = (int*)H3;   // alias: consumed (passC) before H3 written (layer 3)

    const int* src = ei;
    const int* dst = ei + E;

    const int BT = 256;
    int gP  = (N * 5 + BT - 1) / BT;
    int gPB = (E + PB_TILE - 1) / PB_TILE;

    // ---- CSR build: bucket hist -> 196-scan -> run-reserving partition -> local scatter ----
    hipMemsetAsync(bcnt, 0, (size_t)B * sizeof(int), stream);
    k_bhist<<<gPB, PB_T, 0, stream>>>(dst, bcnt, E, B);
    k_bscan<<<1, 64, 0, stream>>>(bcnt, bbase2, bcur, base, B, N, E);
    k_passB<<<gPB, PB_T, 0, stream>>>(src, dst, bcur, stage, E, B);
    k_passC<<<B, 512, 0, stream>>>(stage, bbase2, base, dinv, csr, N);
    k_prescale<<<gP, BT, 0, stream>>>(x, dinv, xs, N * 5);

    // ---- fused layers (pipelined gathers; LDS weights; grid-stride over nodes) ----
    k_layer1<<<LGRID, BT, 0, stream>>>(xs, HS1, csr, base, dinv,
                                       W1, b1, g1, be1, rm1, rv1, N);
    k_layer<1><<<LGRID, BT, 0, stream>>>(HS1, HS2, csr, base, dinv,
                                         W2, b2, g2, be2, rm2, rv2, N);
    k_layer<0><<<LGRID, BT, 0, stream>>>(HS2, H3, csr, base, dinv,
                                         W3, b3, g3, be3, rm3, rv3, N);

    // ---- pool + MLP head ----
    k_pool_fc<<<G, BT, 0, stream>>>(H3, batch, Wf1, bf1, Wf2, bf2, out, N);
}